// Round 13
// baseline (9044.627 us; speedup 1.0000x reference)
//
#include <hip/hip_runtime.h>
#include <math.h>

#define CKCH 512
#define NLEV 10
#define NBATCH 4
#define NSEQ 1024
#define TWO_PI_F 6.2831853071795864769f
#define INV_SQRT2 0.70710678118654752440f
#define IC 8
#define EP 16   // einsum i-partitions
#define ICPS 4  // small-conv i-partitions
#define WTS ((size_t)CKCH * CKCH * 7)   // one transposed weight tensor (floats)

// ---------------------------------------------------------------------------
__device__ __forceinline__ void get_affine(const double* st, long ntot, int subMean,
                                           float& r, float& madj) {
  r = 1.f; madj = 0.f;
  if (!st) return;
  double s1 = st[0], s2 = st[1];
  double mean = s1 / (double)ntot;
  double var = (s2 - s1 * mean) / (double)(ntot - 1);
  double rs = 1.0 / sqrt(var);
  r = (float)rs;
  madj = subMean ? (float)(-mean * rs) : 0.f;
}

template<int NTHR>
__device__ __forceinline__ void block_stats(float s, float s2, double* st, int tid) {
  if constexpr (NTHR <= 64) {
    #pragma unroll
    for (int off = NTHR / 2; off > 0; off >>= 1) {
      s += __shfl_down(s, off);
      s2 += __shfl_down(s2, off);
    }
    if (tid == 0) { atomicAdd(st, (double)s); atomicAdd(st + 1, (double)s2); }
  } else {
    #pragma unroll
    for (int off = 32; off > 0; off >>= 1) {
      s += __shfl_down(s, off);
      s2 += __shfl_down(s2, off);
    }
    __shared__ float sh1[NTHR / 64], sh2[NTHR / 64];
    int w = tid >> 6;
    if ((tid & 63) == 0) { sh1[w] = s; sh2[w] = s2; }
    __syncthreads();
    if (tid == 0) {
      float a = 0.f, b = 0.f;
      #pragma unroll
      for (int i = 0; i < NTHR / 64; ++i) { a += sh1[i]; b += sh2[i]; }
      atomicAdd(st, (double)a); atomicAdd(st + 1, (double)b);
    }
  }
}

// XCD-chunked swizzle: contiguous logical ranges per XCD (weight-group major).
__device__ __forceinline__ void xcd_map(int& bx, int& by, int& bz) {
  int nbx = gridDim.x, nby = gridDim.y, nbz = gridDim.z;
  int Nb = nbx * nby * nbz;
  int h = blockIdx.x + nbx * (blockIdx.y + nby * blockIdx.z);
  int lg = ((Nb & 7) == 0) ? ((h & 7) * (Nb >> 3) + (h >> 3)) : h;
  int R = nbx * nbz;
  int grp = lg / R, rr = lg % R;
  bx = rr % nbx;
  bz = rr / nbx;
  by = grp;
}

// ---------------------------------------------------------------------------
// One-time weight transpose: Wt[(o*7+f)*512 + i] = W[(o*512+i)*7 + f]
// ---------------------------------------------------------------------------
__global__ __launch_bounds__(256) void k_wt(const float* __restrict__ src,
                                            float* __restrict__ dst) {
  int idx = blockIdx.x * 256 + threadIdx.x;
  if (idx >= (int)WTS) return;
  int i = idx & 511;
  int r = idx >> 9;
  int f = r % 7, o = r / 7;
  dst[idx] = src[(size_t)o * 3584 + i * 7 + f];
}

// ---------------------------------------------------------------------------
#define TT1 8
__global__ __launch_bounds__(256) void k_l1t(const float* __restrict__ vals,
                                             const float* __restrict__ w,
                                             const float* __restrict__ bias,
                                             float* __restrict__ out) {
  __shared__ float sh[TT1][256];
  int b = blockIdx.z;
  int t0 = blockIdx.x * TT1;
  int tid = threadIdx.x;
  for (int i = tid; i < TT1 * 256; i += 256) {
    int tt = i >> 8, d = i & 255;
    sh[tt][d] = vals[((size_t)(b * NSEQ + t0 + tt)) * 256 + d];
  }
  __syncthreads();
  for (int k = tid; k < CKCH; k += 256) {
    float acc[TT1];
    #pragma unroll
    for (int tt = 0; tt < TT1; ++tt) acc[tt] = 0.f;
    const float* wr = w + (size_t)k * 256;
    for (int d = 0; d < 256; ++d) {
      float wv = wr[d];
      #pragma unroll
      for (int tt = 0; tt < TT1; ++tt) acc[tt] += sh[tt][d] * wv;
    }
    float bv = bias[k];
    #pragma unroll
    for (int tt = 0; tt < TT1; ++tt)
      out[(size_t)b * CKCH * NSEQ + (size_t)k * NSEQ + (t0 + tt)] = acc[tt] + bv;
  }
}

// ---------------------------------------------------------------------------
// DUAL-branch partial-sum tiled stride-2 conv, XCD-swizzled + reg-prefetched.
// (round-10 measured-best configuration)
// ---------------------------------------------------------------------------
template<int TT>
__global__ __launch_bounds__((TT / 4) * 8) void k_conv2_pd(
    const float* __restrict__ X, size_t xbs,
    const double* __restrict__ st, long ntot, int subMean,
    const float* __restrict__ WtH, const float* __restrict__ WtL,
    float* __restrict__ PH, float* __restrict__ PL, int L, int ICP) {
  constexpr int SP = 2 * TT + 8;
  constexpr int NTHR = (TT / 4) * 8;
  constexpr int SPAN = 2 * TT + 6;
  constexpr int NQ = TT / 2 + 3;
  constexpr int XTRIPS = (IC * NQ + NTHR - 1) / NTHR;
  constexpr int WCNT = 32 * 7 * (IC / 4);
  constexpr int WTRIPS = (WCNT + NTHR - 1) / NTHR;
  __shared__ float Xs[IC][SP];
  __shared__ float WsH[IC][32][8], WsL[IC][32][8];
  int tx = threadIdx.x, ty = threadIdx.y;
  int tid = ty * (TT / 4) + tx;
  int bxx, byy, bzz;
  xcd_map(bxx, byy, bzz);
  int b = bzz;
  int t0 = bxx * TT;
  int o0 = (byy & 15) * 32;
  int w = byy >> 4;
  int Lh = L >> 1;
  float r, madj;
  get_affine(st, ntot, subMean, r, madj);
  const float* Xb = X + (size_t)b * xbs;
  int pbase = 2 * t0 - 3;
  int ps = pbase & ~3;
  float accH[4][4], accL[4][4];
  #pragma unroll
  for (int i = 0; i < 4; ++i)
    #pragma unroll
    for (int j = 0; j < 4; ++j) { accH[i][j] = 0.f; accL[i][j] = 0.f; }

  float vx[XTRIPS][4];
  float4 wh_[WTRIPS], wl_[WTRIPS];

  auto loadX = [&](int i0) {
    #pragma unroll
    for (int tr = 0; tr < XTRIPS; ++tr) {
      int idx = tid + tr * NTHR;
      if (idx < IC * NQ) {
        int ii = idx / NQ, qq = idx % NQ;
        int p4 = ps + 4 * qq;
        const float* xr = Xb + (size_t)(i0 + ii) * L;
        if (p4 >= 0 && p4 + 3 < L) {
          float4 t = *(const float4*)&xr[p4];
          vx[tr][0] = t.x; vx[tr][1] = t.y; vx[tr][2] = t.z; vx[tr][3] = t.w;
        } else {
          #pragma unroll
          for (int e = 0; e < 4; ++e) {
            int p = p4 + e;
            vx[tr][e] = (p >= 0 && p < L) ? xr[p] : 0.f;
          }
        }
      }
    }
  };
  auto loadW = [&](int i0) {
    #pragma unroll
    for (int tr = 0; tr < WTRIPS; ++tr) {
      int idx = tid + tr * NTHR;
      if (idx < WCNT) {
        int q = idx % (IC / 4);
        int rest = idx / (IC / 4);
        int f = rest % 7, o = rest / 7;
        size_t gb = ((size_t)(o0 + o) * 7 + f) * 512 + i0 + 4 * q;
        wh_[tr] = *(const float4*)&WtH[gb];
        wl_[tr] = *(const float4*)&WtL[gb];
      }
    }
  };
  auto writeLDS = [&]() {
    #pragma unroll
    for (int tr = 0; tr < XTRIPS; ++tr) {
      int idx = tid + tr * NTHR;
      if (idx < IC * NQ) {
        int ii = idx / NQ, qq = idx % NQ;
        int p4 = ps + 4 * qq;
        #pragma unroll
        for (int e = 0; e < 4; ++e) {
          int p = p4 + e;
          int pp = p - pbase;
          if ((unsigned)pp < (unsigned)SPAN) {
            bool ok = (p >= 0 && p < L);
            Xs[ii][pp] = ok ? fmaf(vx[tr][e], r, madj) : 0.f;
          }
        }
      }
    }
    #pragma unroll
    for (int tr = 0; tr < WTRIPS; ++tr) {
      int idx = tid + tr * NTHR;
      if (idx < WCNT) {
        int q = idx % (IC / 4);
        int rest = idx / (IC / 4);
        int f = rest % 7, o = rest / 7;
        WsH[4 * q + 0][o][f] = wh_[tr].x; WsH[4 * q + 1][o][f] = wh_[tr].y;
        WsH[4 * q + 2][o][f] = wh_[tr].z; WsH[4 * q + 3][o][f] = wh_[tr].w;
        WsL[4 * q + 0][o][f] = wl_[tr].x; WsL[4 * q + 1][o][f] = wl_[tr].y;
        WsL[4 * q + 2][o][f] = wl_[tr].z; WsL[4 * q + 3][o][f] = wl_[tr].w;
      }
    }
  };

  int cpp = (CKCH / IC) / ICP;
  int icBeg = w * cpp, icEnd = icBeg + cpp;
  loadX(icBeg * IC);
  loadW(icBeg * IC);
  for (int ic = icBeg; ic < icEnd; ++ic) {
    if (ic != icBeg) __syncthreads();
    writeLDS();
    __syncthreads();
    if (ic + 1 < icEnd) { loadX((ic + 1) * IC); loadW((ic + 1) * IC); }
    #pragma unroll
    for (int ii = 0; ii < IC; ++ii) {
      float xv[16];
      #pragma unroll
      for (int u = 0; u < 4; ++u)
        *(float4*)&xv[4 * u] = *(const float4*)&Xs[ii][8 * tx + 4 * u];
      #pragma unroll
      for (int oo = 0; oo < 4; ++oo) {
        float wh[8], wl[8];
        *(float4*)&wh[0] = *(const float4*)&WsH[ii][ty + 8 * oo][0];
        *(float4*)&wh[4] = *(const float4*)&WsH[ii][ty + 8 * oo][4];
        *(float4*)&wl[0] = *(const float4*)&WsL[ii][ty + 8 * oo][0];
        *(float4*)&wl[4] = *(const float4*)&WsL[ii][ty + 8 * oo][4];
        #pragma unroll
        for (int tt = 0; tt < 4; ++tt)
          #pragma unroll
          for (int f = 0; f < 7; ++f) {
            float x = xv[2 * tt + f];
            accH[oo][tt] = fmaf(x, wh[f], accH[oo][tt]);
            accL[oo][tt] = fmaf(x, wl[f], accL[oo][tt]);
          }
      }
    }
  }
  size_t pb = ((size_t)w * NBATCH + b) * ((size_t)CKCH * Lh);
  #pragma unroll
  for (int oo = 0; oo < 4; ++oo) {
    int o = o0 + ty + 8 * oo;
    float4 vh = make_float4(accH[oo][0], accH[oo][1], accH[oo][2], accH[oo][3]);
    float4 vl = make_float4(accL[oo][0], accL[oo][1], accL[oo][2], accL[oo][3]);
    *(float4*)&PH[pb + (size_t)o * Lh + t0 + 4 * tx] = vh;
    *(float4*)&PL[pb + (size_t)o * Lh + t0 + 4 * tx] = vl;
  }
}

// dual vectorized reduce + biases
__global__ __launch_bounds__(256) void k_red2d(const float* __restrict__ PH,
                                               const float* __restrict__ PL,
                                               const float* __restrict__ bH,
                                               const float* __restrict__ bL,
                                               float* __restrict__ YH,
                                               float* __restrict__ YL, size_t ybs,
                                               int Lh, int ICP, int lhbits) {
  long i4 = (long)blockIdx.x * 256 + threadIdx.x;
  const long per4 = (long)CKCH * Lh / 4;
  int b = (int)(i4 / per4);
  long rem4 = (i4 % per4) * 4;
  int o = (int)(rem4 >> lhbits);
  const size_t pstr = (size_t)NBATCH * CKCH * Lh;
  size_t base = (size_t)b * CKCH * Lh + rem4;
  float4 sh = make_float4(0.f, 0.f, 0.f, 0.f);
  float4 sl = make_float4(0.f, 0.f, 0.f, 0.f);
  for (int w = 0; w < ICP; ++w) {
    float4 vh = *(const float4*)&PH[(size_t)w * pstr + base];
    float4 vl = *(const float4*)&PL[(size_t)w * pstr + base];
    sh.x += vh.x; sh.y += vh.y; sh.z += vh.z; sh.w += vh.w;
    sl.x += vl.x; sl.y += vl.y; sl.z += vl.z; sl.w += vl.w;
  }
  float bvh = bH[o], bvl = bL[o];
  sh.x += bvh; sh.y += bvh; sh.z += bvh; sh.w += bvh;
  sl.x += bvl; sl.y += bvl; sl.z += bvl; sl.w += bvl;
  *(float4*)&YH[(size_t)b * ybs + rem4] = sh;
  *(float4*)&YL[(size_t)b * ybs + rem4] = sl;
}

// ---------------------------------------------------------------------------
// Small-level DUAL-branch stride-2 conv (original weight layout)
// ---------------------------------------------------------------------------
__global__ __launch_bounds__(256) void k_conv2_sd(
    const float* __restrict__ X, size_t xbs,
    const double* __restrict__ st, long ntot, int subMean,
    const float* __restrict__ WH, const float* __restrict__ WL,
    float* __restrict__ PH, float* __restrict__ PL, int L) {
  int Lh = L >> 1;
  int lane = threadIdx.x & 63;
  int gw = blockIdx.x * 4 + (threadIdx.x >> 6);
  int b = __builtin_amdgcn_readfirstlane(gw >> 9);
  int o = __builtin_amdgcn_readfirstlane(gw & 511);
  int w = blockIdx.y;
  float r, madj;
  get_affine(st, ntot, subMean, r, madj);
  const float* Xb = X + (size_t)b * xbs;
  int p0 = 2 * lane - 3;
  int pc[7]; float msk[7];
  #pragma unroll
  for (int u = 0; u < 7; ++u) {
    int p = p0 + u;
    bool ok = (p >= 0 && p < L);
    pc[u] = ok ? p : 0;
    msk[u] = ok ? 1.f : 0.f;
  }
  const int cpi = CKCH / ICPS;
  const float* wh0 = WH + (size_t)o * (CKCH * 7);
  const float* wl0 = WL + (size_t)o * (CKCH * 7);
  float accH = 0.f, accL = 0.f;
  #pragma unroll 2
  for (int i = w * cpi; i < (w + 1) * cpi; ++i) {
    const float* xr = Xb + (size_t)i * L;
    float xv[7];
    #pragma unroll
    for (int u = 0; u < 7; ++u)
      xv[u] = msk[u] * fmaf(xr[pc[u]], r, madj);
    const float* wh = wh0 + i * 7;
    const float* wl = wl0 + i * 7;
    #pragma unroll
    for (int f = 0; f < 7; ++f) {
      accH = fmaf(xv[f], wh[f], accH);
      accL = fmaf(xv[f], wl[f], accL);
    }
  }
  if (lane < Lh) {
    size_t idx = ((size_t)w * NBATCH + b) * ((size_t)CKCH * Lh) + (size_t)o * Lh + lane;
    PH[idx] = accH;
    PL[idx] = accL;
  }
}

__global__ __launch_bounds__(256) void k_red2s(const float* __restrict__ PH,
                                               const float* __restrict__ PL,
                                               const float* __restrict__ bH,
                                               const float* __restrict__ bL,
                                               float* __restrict__ YH, size_t ybsH,
                                               float* __restrict__ YL, size_t ybsL,
                                               int Lh, int lhbits, long tot) {
  long idx = (long)blockIdx.x * 256 + threadIdx.x;
  if (idx >= tot) return;
  const long per = (long)CKCH * Lh;
  int b = (int)(idx / per);
  long rem = idx % per;
  int o = (int)(rem >> lhbits);
  const size_t pstr = (size_t)NBATCH * CKCH * Lh;
  size_t base = (size_t)b * per + rem;
  float sh = 0.f, sl = 0.f;
  #pragma unroll
  for (int w = 0; w < ICPS; ++w) {
    sh += PH[(size_t)w * pstr + base];
    sl += PL[(size_t)w * pstr + base];
  }
  YH[(size_t)b * ybsH + rem] = sh + bH[o];
  YL[(size_t)b * ybsL + rem] = sl + bL[o];
}

// ---------------------------------------------------------------------------
// Partial-sum tiled reconstruction conv, XCD-swizzled + reg-prefetched.
// (round-10 measured-best configuration)
// ---------------------------------------------------------------------------
template<int TT>
__global__ __launch_bounds__((TT / 4) * 8) void k_conv_rec_p(
    const float* __restrict__ A, size_t abs_,
    const double* __restrict__ stA, long ntA, int smA,
    const float* __restrict__ D, size_t dbs,
    const double* __restrict__ stD, long ntD,
    const float* __restrict__ WtA, const float* __restrict__ WtD,
    float* __restrict__ P, int Ld, int ICP) {
  constexpr int QS = TT / 2 + 8;
  constexpr int NTHR = (TT / 4) * 8;
  constexpr int SPANQ = TT / 2 + 4;
  constexpr int NQ = TT / 8 + 3;
  constexpr int XTRIPS = (IC * NQ + NTHR - 1) / NTHR;
  constexpr int WCNT = 32 * 7 * (IC / 4);
  constexpr int WTRIPS = (WCNT + NTHR - 1) / NTHR;
  __shared__ float As[IC][QS], Ds[IC][QS];
  __shared__ float Was[IC][32][8], Wds[IC][32][8];
  int tx = threadIdx.x, ty = threadIdx.y;
  int tid = ty * (TT / 4) + tx;
  int bxx, byy, bzz;
  xcd_map(bxx, byy, bzz);
  int b = bzz;
  int t0 = bxx * TT;
  int o0 = (byy & 15) * 32;
  int w = byy >> 4;
  int L2 = Ld * 2;
  float rA, mA, rD, mD;
  get_affine(stA, ntA, smA, rA, mA);
  get_affine(stD, ntD, 1, rD, mD);
  const float* Ab = A + (size_t)b * abs_;
  const float* Db = D + (size_t)b * dbs;
  int q0 = t0 / 2 - 2;
  int qs = q0 & ~3;
  float acc[4][4];
  #pragma unroll
  for (int i = 0; i < 4; ++i)
    #pragma unroll
    for (int j = 0; j < 4; ++j) acc[i][j] = 0.f;

  float va_r[XTRIPS][4], vd_r[XTRIPS][4];
  float4 wa_r[WTRIPS], wd_r[WTRIPS];

  auto loadX = [&](int i0) {
    #pragma unroll
    for (int tr = 0; tr < XTRIPS; ++tr) {
      int idx = tid + tr * NTHR;
      if (idx < IC * NQ) {
        int ii = idx / NQ, qq = idx % NQ;
        int q4 = qs + 4 * qq;
        const float* ar = Ab + (size_t)(i0 + ii) * Ld;
        const float* dr = Db + (size_t)(i0 + ii) * Ld;
        if (q4 >= 0 && q4 + 3 < Ld) {
          float4 ta = *(const float4*)&ar[q4];
          float4 td = *(const float4*)&dr[q4];
          va_r[tr][0] = ta.x; va_r[tr][1] = ta.y; va_r[tr][2] = ta.z; va_r[tr][3] = ta.w;
          vd_r[tr][0] = td.x; vd_r[tr][1] = td.y; vd_r[tr][2] = td.z; vd_r[tr][3] = td.w;
        } else {
          #pragma unroll
          for (int e = 0; e < 4; ++e) {
            int q = q4 + e;
            bool ok = (q >= 0 && q < Ld);
            va_r[tr][e] = ok ? ar[ok ? q : 0] : 0.f;
            vd_r[tr][e] = ok ? dr[ok ? q : 0] : 0.f;
          }
        }
      }
    }
  };
  auto loadW = [&](int i0) {
    #pragma unroll
    for (int tr = 0; tr < WTRIPS; ++tr) {
      int idx = tid + tr * NTHR;
      if (idx < WCNT) {
        int q = idx % (IC / 4);
        int rest = idx / (IC / 4);
        int f = rest % 7, o = rest / 7;
        size_t gb = ((size_t)(o0 + o) * 7 + f) * 512 + i0 + 4 * q;
        wa_r[tr] = *(const float4*)&WtA[gb];
        wd_r[tr] = *(const float4*)&WtD[gb];
      }
    }
  };
  auto writeLDS = [&]() {
    #pragma unroll
    for (int tr = 0; tr < XTRIPS; ++tr) {
      int idx = tid + tr * NTHR;
      if (idx < IC * NQ) {
        int ii = idx / NQ, qq = idx % NQ;
        int q4 = qs + 4 * qq;
        #pragma unroll
        for (int e = 0; e < 4; ++e) {
          int q = q4 + e;
          int qq2 = q - q0;
          if ((unsigned)qq2 < (unsigned)SPANQ) {
            bool ok = (q >= 0 && q < Ld);
            As[ii][qq2] = ok ? fmaf(va_r[tr][e], rA, mA) : 0.f;
            Ds[ii][qq2] = ok ? fmaf(vd_r[tr][e], rD, mD) : 0.f;
          }
        }
      }
    }
    #pragma unroll
    for (int tr = 0; tr < WTRIPS; ++tr) {
      int idx = tid + tr * NTHR;
      if (idx < WCNT) {
        int q = idx % (IC / 4);
        int rest = idx / (IC / 4);
        int f = rest % 7, o = rest / 7;
        Was[4 * q + 0][o][f] = wa_r[tr].x; Was[4 * q + 1][o][f] = wa_r[tr].y;
        Was[4 * q + 2][o][f] = wa_r[tr].z; Was[4 * q + 3][o][f] = wa_r[tr].w;
        Wds[4 * q + 0][o][f] = wd_r[tr].x; Wds[4 * q + 1][o][f] = wd_r[tr].y;
        Wds[4 * q + 2][o][f] = wd_r[tr].z; Wds[4 * q + 3][o][f] = wd_r[tr].w;
      }
    }
  };

  int cpp = (CKCH / IC) / ICP;
  int icBeg = w * cpp, icEnd = icBeg + cpp;
  loadX(icBeg * IC);
  loadW(icBeg * IC);
  for (int ic = icBeg; ic < icEnd; ++ic) {
    if (ic != icBeg) __syncthreads();
    writeLDS();
    __syncthreads();
    if (ic + 1 < icEnd) { loadX((ic + 1) * IC); loadW((ic + 1) * IC); }
    #pragma unroll
    for (int ii = 0; ii < IC; ++ii) {
      float av[6], dv[6];
      #pragma unroll
      for (int u = 0; u < 3; ++u) {
        *(float2*)&av[2 * u] = *(const float2*)&As[ii][2 * tx + 2 * u];
        *(float2*)&dv[2 * u] = *(const float2*)&Ds[ii][2 * tx + 2 * u];
      }
      #pragma unroll
      for (int oo = 0; oo < 4; ++oo) {
        float wa[8], wd[8];
        *(float4*)&wa[0] = *(const float4*)&Was[ii][ty + 8 * oo][0];
        *(float4*)&wa[4] = *(const float4*)&Was[ii][ty + 8 * oo][4];
        *(float4*)&wd[0] = *(const float4*)&Wds[ii][ty + 8 * oo][0];
        *(float4*)&wd[4] = *(const float4*)&Wds[ii][ty + 8 * oo][4];
        #pragma unroll
        for (int tt = 0; tt < 4; ++tt) {
          #pragma unroll
          for (int f = 0; f < 7; ++f) {
            const int u = ((tt + f - 3) >> 1) + 2;
            acc[oo][tt] = fmaf(av[u], wa[f], acc[oo][tt]);
            acc[oo][tt] = fmaf(dv[u], wd[f], acc[oo][tt]);
          }
        }
      }
    }
  }
  float* Pb = P + ((size_t)w * NBATCH + b) * ((size_t)CKCH * L2);
  #pragma unroll
  for (int oo = 0; oo < 4; ++oo) {
    int o = o0 + ty + 8 * oo;
    float4 v = make_float4(acc[oo][0], acc[oo][1], acc[oo][2], acc[oo][3]);
    *(float4*)&Pb[(size_t)o * L2 + t0 + 4 * tx] = v;
  }
}

__global__ __launch_bounds__(256) void k_red_rec(const float* __restrict__ P,
                                                 const float* __restrict__ bA,
                                                 const float* __restrict__ bD,
                                                 float* __restrict__ S, size_t sbs,
                                                 int L2, int ICP, int lhbits,
                                                 double* __restrict__ stOut) {
  long i4 = (long)blockIdx.x * 256 + threadIdx.x;
  const long per4 = (long)CKCH * L2 / 4;
  int b = (int)(i4 / per4);
  long rem4 = (i4 % per4) * 4;
  int o = (int)(rem4 >> lhbits);
  const size_t pstr = (size_t)NBATCH * CKCH * L2;
  float4 s = *(const float4*)&P[(size_t)b * CKCH * L2 + rem4];
  for (int w = 1; w < ICP; ++w) {
    float4 v = *(const float4*)&P[(size_t)w * pstr + (size_t)b * CKCH * L2 + rem4];
    s.x += v.x; s.y += v.y; s.z += v.z; s.w += v.w;
  }
  float bv = bA[o] + bD[o];
  s.x += bv; s.y += bv; s.z += bv; s.w += bv;
  *(float4*)&S[(size_t)b * sbs + rem4] = s;
  float ss = s.x + s.y + s.z + s.w;
  float s2 = s.x * s.x + s.y * s.y + s.z * s.z + s.w * s.w;
  block_stats<256>(ss, s2, stOut, threadIdx.x);
}

// ---------------------------------------------------------------------------
// Small-level reconstruction (original weight layout)
// ---------------------------------------------------------------------------
__global__ __launch_bounds__(256) void k_conv_rec_sp(
    const float* __restrict__ A, size_t abs_,
    const double* __restrict__ stA, long ntA, int smA,
    const float* __restrict__ D, size_t dbs,
    const double* __restrict__ stD, long ntD,
    const float* __restrict__ WA, const float* __restrict__ WD,
    float* __restrict__ P, int Ld) {
  int L2 = Ld * 2;
  int lane = threadIdx.x & 63;
  int gw = blockIdx.x * 4 + (threadIdx.x >> 6);
  int b = __builtin_amdgcn_readfirstlane(gw >> 9);
  int o = __builtin_amdgcn_readfirstlane(gw & 511);
  int w = blockIdx.y;
  float rA, mA, rD, mD;
  get_affine(stA, ntA, smA, rA, mA);
  get_affine(stD, ntD, 1, rD, mD);
  const float* Ab = A + (size_t)b * abs_;
  const float* Db = D + (size_t)b * dbs;
  const float* wa0 = WA + (size_t)o * (CKCH * 7);
  const float* wd0 = WD + (size_t)o * (CKCH * 7);
  int t = lane;
  int qt0 = (t - 3) >> 1;
  int par = t & 1;
  int qc[4]; float mskq[4];
  #pragma unroll
  for (int u = 0; u < 4; ++u) {
    int q = qt0 + u;
    bool ok = (q >= 0 && q < Ld);
    qc[u] = ok ? q : 0;
    mskq[u] = ok ? 1.f : 0.f;
  }
  const int cpi = CKCH / ICPS;
  float acc = 0.f;
  #pragma unroll 2
  for (int i = w * cpi; i < (w + 1) * cpi; ++i) {
    const float* ar = Ab + (size_t)i * Ld;
    const float* dr = Db + (size_t)i * Ld;
    float av[4], dv[4];
    #pragma unroll
    for (int u = 0; u < 4; ++u) {
      av[u] = mskq[u] * fmaf(ar[qc[u]], rA, mA);
      dv[u] = mskq[u] * fmaf(dr[qc[u]], rD, mD);
    }
    const float* wa = wa0 + i * 7;
    const float* wd = wd0 + i * 7;
    #pragma unroll
    for (int f = 0; f < 7; ++f) {
      const int ue = (f + 1) >> 1;
      const int uo = f >> 1;
      float ax = par ? av[uo] : av[ue];
      float dx = par ? dv[uo] : dv[ue];
      acc = fmaf(ax, wa[f], acc);
      acc = fmaf(dx, wd[f], acc);
    }
  }
  if (t < L2)
    P[((size_t)w * NBATCH + b) * ((size_t)CKCH * L2) + (size_t)o * L2 + t] = acc;
}

__global__ __launch_bounds__(256) void k_red_recs(const float* __restrict__ P,
                                                  const float* __restrict__ bA,
                                                  const float* __restrict__ bD,
                                                  float* __restrict__ S, size_t sbs,
                                                  int L2, int lhbits, long tot,
                                                  double* __restrict__ stOut) {
  long idx = (long)blockIdx.x * 256 + threadIdx.x;
  float val = 0.f;
  if (idx < tot) {
    const long per = (long)CKCH * L2;
    int b = (int)(idx / per);
    long rem = idx % per;
    int o = (int)(rem >> lhbits);
    const size_t pstr = (size_t)NBATCH * CKCH * L2;
    size_t base = (size_t)b * per + rem;
    float s = 0.f;
    #pragma unroll
    for (int w = 0; w < ICPS; ++w) s += P[(size_t)w * pstr + base];
    val = s + bA[o] + bD[o];
    S[(size_t)b * sbs + rem] = val;
  }
  block_stats<256>(val, val * val, stOut, threadIdx.x);
}

// ---------------------------------------------------------------------------
__global__ void k_mktw(float2* tw) {
  int p = blockIdx.x * 256 + threadIdx.x;
  if (p < 1024) {
    float s, c;
    sincosf(TWO_PI_F * (float)p * (1.0f / 1024.0f), &s, &c);
    tw[p] = make_float2(c, s);
  }
}

// ---------------------------------------------------------------------------
__global__ __launch_bounds__(256) void k_dft2b(const float* __restrict__ H0,
                                               const float* __restrict__ H1, size_t hbs,
                                               const float2* __restrict__ tw,
                                               float* __restrict__ xfr, float* __restrict__ xfi,
                                               int Lh, int l) {
  __shared__ float Hs[64][65];
  __shared__ float2 tws[1024];
  int tx = threadIdx.x, ty = threadIdx.y;
  int tid = ty * 64 + tx;
  for (int idx = tid; idx < 1024; idx += 256) tws[idx] = tw[idx];
  int k = blockIdx.x * 64 + tx;
  int x = blockIdx.y * 4 + ty;
  int z = blockIdx.z;
  int br = z >> 2, b = z & 3;
  const float* Hb = (br ? H1 : H0) + (size_t)b * hbs;
  int step = 1024 / Lh;
  int dp = (x * step) & 1023;
  float ar = 0.f, ai = 0.f;
  for (int m0 = 0; m0 < Lh; m0 += 64) {
    int mc = min(64, Lh - m0);
    __syncthreads();
    for (int idx = tid; idx < mc * 64; idx += 256) {
      int mm = idx >> 6, kk = idx & 63;
      Hs[mm][kk] = Hb[(size_t)(m0 + mm) * CKCH + blockIdx.x * 64 + kk];
    }
    __syncthreads();
    int p = (int)(((long)dp * m0) & 1023);
    for (int mm = 0; mm < mc; ++mm) {
      float2 w = tws[p];
      float v = Hs[mm][tx];
      ar = fmaf(v, w.x, ar);
      ai = fmaf(v, -w.y, ai);
      p = (p + dp) & 1023;
    }
  }
  if (x < l) {
    size_t base = ((size_t)(br * NBATCH + b) * CKCH + k) * 16 + x;
    xfr[base] = ar;
    xfi[base] = ai;
  }
}

// ---------------------------------------------------------------------------
__global__ __launch_bounds__(256) void k_einsum2(const float* __restrict__ xfr,
                                                 const float* __restrict__ xfi,
                                                 const float* __restrict__ hwr,
                                                 const float* __restrict__ hwi,
                                                 const float* __restrict__ lwr,
                                                 const float* __restrict__ lwi,
                                                 float* __restrict__ outr,
                                                 float* __restrict__ outi, int l) {
  int gid = blockIdx.x * 256 + threadIdx.x;
  int o = gid >> 4, x = gid & 15;
  if (x >= l) return;
  int part = blockIdx.y;
  int br = blockIdx.z;
  const float* wr = br ? lwr : hwr;
  const float* wi = br ? lwi : hwi;
  int i0 = part * (CKCH / EP);
  float ar[NBATCH] = {0, 0, 0, 0}, ai[NBATCH] = {0, 0, 0, 0};
  size_t xoff = (size_t)(br * NBATCH) * CKCH * 16;
  for (int i = i0; i < i0 + CKCH / EP; ++i) {
    float wre = wr[((size_t)i * CKCH + o) * 16 + x];
    float wim = wi[((size_t)i * CKCH + o) * 16 + x];
    #pragma unroll
    for (int b = 0; b < NBATCH; ++b) {
      float xre = xfr[xoff + ((size_t)b * CKCH + i) * 16 + x];
      float xim = xfi[xoff + ((size_t)b * CKCH + i) * 16 + x];
      ar[b] += xre * wre - xim * wim;
      ai[b] += xre * wim + xim * wre;
    }
  }
  size_t pb = (size_t)part * (2 * NBATCH * CKCH * 16) + xoff;
  #pragma unroll
  for (int b = 0; b < NBATCH; ++b) {
    outr[pb + ((size_t)b * CKCH + o) * 16 + x] = ar[b];
    outi[pb + ((size_t)b * CKCH + o) * 16 + x] = ai[b];
  }
}

// ---------------------------------------------------------------------------
__global__ __launch_bounds__(256) void k_irfft2b(const float* __restrict__ outr,
                                                 const float* __restrict__ outi,
                                                 const float2* __restrict__ tw,
                                                 float* __restrict__ YH, size_t ybsH,
                                                 double* __restrict__ stH,
                                                 float* __restrict__ YL, size_t ybsL,
                                                 double* __restrict__ stL,
                                                 int Lh, int l) {
  int k = blockIdx.x * 256 + threadIdx.x;
  int z = blockIdx.z;
  int br = z >> 2, b = z & 3;
  int t0 = blockIdx.y * 4;
  int step = 1024 / Lh;
  float invL = 1.0f / (float)Lh;
  float acc[4] = {0.f, 0.f, 0.f, 0.f};
  size_t base = ((size_t)(br * NBATCH + b) * CKCH + k) * 16;
  const size_t pstride = (size_t)2 * NBATCH * CKCH * 16;
  for (int x = 0; x < l; ++x) {
    float re = 0.f, im = 0.f;
    #pragma unroll
    for (int p = 0; p < EP; ++p) {
      re += outr[p * pstride + base + x];
      im += outi[p * pstride + base + x];
    }
    float coef = (x == 0 || 2 * x == Lh) ? 1.f : 2.f;
    float cre = coef * re, cim = coef * im;
    #pragma unroll
    for (int tt = 0; tt < 4; ++tt) {
      int t = t0 + tt;
      int p = (x * t * step) & 1023;
      float2 w = tw[p];
      acc[tt] = fmaf(cre, w.x, fmaf(-cim, w.y, acc[tt]));
    }
  }
  float* Y = br ? YL : YH;
  size_t ybs = br ? ybsL : ybsH;
  double* st = br ? stL : stH;
  float s = 0.f, s2 = 0.f;
  float* Yb = Y + (size_t)b * ybs;
  #pragma unroll
  for (int tt = 0; tt < 4; ++tt) {
    int t = t0 + tt;
    if (t < Lh) {
      float y = acc[tt] * invL;
      Yb[(size_t)t * CKCH + k] = y;
      s += y; s2 += y * y;
    }
  }
  block_stats<256>(s, s2, st, threadIdx.x);
}

// ---------------------------------------------------------------------------
__global__ __launch_bounds__(256) void k_permute_relu(const float* __restrict__ in,
                                                      const double* __restrict__ st, long ntot,
                                                      float* __restrict__ out) {
  long idx = (long)blockIdx.x * 256 + threadIdx.x;
  const long total = (long)NBATCH * CKCH * NSEQ;
  if (idx >= total) return;
  float r, madj;
  get_affine(st, ntot, 0, r, madj);
  int b = (int)(idx / (CKCH * NSEQ));
  int rr = (int)(idx % (CKCH * NSEQ));
  int k = rr / NSEQ, t = rr % NSEQ;
  float v = in[(size_t)b * CKCH * NSEQ + (size_t)t * CKCH + k] * r;
  out[idx] = fmaxf(v, 0.f) * INV_SQRT2;
}

// ---------------------------------------------------------------------------
#define TT2 8
__global__ __launch_bounds__(256) void k_l2(const float* __restrict__ Vf,
                                            const double* __restrict__ st, long ntot,
                                            const float* __restrict__ w,
                                            const float* __restrict__ bias,
                                            float* __restrict__ out) {
  __shared__ float sh[TT2][CKCH];
  int b = blockIdx.z;
  int m0 = blockIdx.x * TT2;
  int tid = threadIdx.x;
  float r, madj;
  get_affine(st, ntot, 0, r, madj);
  for (int i = tid; i < TT2 * CKCH; i += 256) {
    int tt = i >> 9, k = i & 511;
    float v = Vf[(size_t)b * CKCH * NSEQ + (size_t)(m0 + tt) * CKCH + k] * r;
    sh[tt][k] = fmaxf(v, 0.f) * INV_SQRT2;
  }
  __syncthreads();
  int o = tid;
  float acc[TT2];
  #pragma unroll
  for (int tt = 0; tt < TT2; ++tt) acc[tt] = 0.f;
  const float* wo = w + (size_t)o * CKCH;
  for (int k = 0; k < CKCH; ++k) {
    float wv = wo[k];
    #pragma unroll
    for (int tt = 0; tt < TT2; ++tt) acc[tt] += sh[tt][k] * wv;
  }
  float bv = bias[o];
  #pragma unroll
  for (int tt = 0; tt < TT2; ++tt)
    out[((size_t)b * NSEQ + m0 + tt) * 256 + o] = acc[tt] + bv;
}

// ---------------------------------------------------------------------------
extern "C" void kernel_launch(void* const* d_in, const int* in_sizes, int n_in,
                              void* d_out, int out_size, void* d_ws, size_t ws_size,
                              hipStream_t stream) {
  const float* values  = (const float*)d_in[2];
  const float* L1w     = (const float*)d_in[4];
  const float* L1b     = (const float*)d_in[5];
  const float* L2w     = (const float*)d_in[6];
  const float* L2b     = (const float*)d_in[7];
  const float* ec_hp_w = (const float*)d_in[8];
  const float* ec_hp_b = (const float*)d_in[9];
  const float* ec_lp_w = (const float*)d_in[10];
  const float* ec_lp_b = (const float*)d_in[11];
  const float* hp_wr   = (const float*)d_in[12];
  const float* hp_wi   = (const float*)d_in[13];
  const float* lp_wr   = (const float*)d_in[14];
  const float* lp_wi   = (const float*)d_in[15];
  const float* rc_lp_w = (const float*)d_in[16];
  const float* rc_lp_b = (const float*)d_in[17];
  const float* rc_hp_w = (const float*)d_in[18];
  const float* rc_hp_b = (const float*)d_in[19];

  double* stats = (double*)d_ws;
  float2* tw = (float2*)((char*)d_ws + 2048);
  float* base = (float*)((char*)d_ws + 12288);
  const size_t AB = (size_t)CKCH * NSEQ;
  const size_t CB = (size_t)CKCH * CKCH;
  const size_t XB = (size_t)CKCH * 16;
  const size_t DB = (size_t)CKCH * 1023;

  float* A   = base;
  float* Bb  = A   + (size_t)NBATCH * AB;
  float* C1  = Bb  + (size_t)NBATCH * AB;
  float* C1L = C1  + (size_t)NBATCH * CB;
  float* XFr = C1L + (size_t)NBATCH * CB;
  float* XFi = XFr + (size_t)2 * NBATCH * XB;
  float* OMr = XFi + (size_t)2 * NBATCH * XB;
  float* OMi = OMr + (size_t)2 * NBATCH * XB * EP;
  float* Dd  = OMi + (size_t)2 * NBATCH * XB * EP;
  float* Wt  = Dd + (size_t)NBATCH * DB;   // 8 transposed weight tensors
  float* PB  = Wt + 8 * WTS;
  size_t used_bytes = 12288 + ((size_t)(PB - base)) * sizeof(float);
  size_t pavail = (ws_size > used_bytes) ? (ws_size - used_bytes) : 0;

  auto pickICP = [&](int len, int ideal, int nbuf) -> int {
    int icp = ideal;
    while (icp > 1 && (size_t)nbuf * icp * NBATCH * CKCH * len * sizeof(float) > pavail)
      icp >>= 1;
    return icp < 1 ? 1 : icp;
  };
  bool smallFit = ((size_t)2 * ICPS * NBATCH * CKCH * 64 * sizeof(float)) <= pavail;

  (void)hipMemsetAsync(stats, 0, 2048, stream);
  k_mktw<<<dim3(4), 256, 0, stream>>>(tw);
  const float* wsrc[8] = {ec_hp_w, ec_hp_w + WTS, ec_lp_w, ec_lp_w + WTS,
                          rc_lp_w, rc_lp_w + WTS, rc_hp_w, rc_hp_w + WTS};
  unsigned wtblocks = (unsigned)((WTS + 255) / 256);
  for (int i = 0; i < 8; ++i)
    k_wt<<<dim3(wtblocks), 256, 0, stream>>>(wsrc[i], Wt + (size_t)i * WTS);

  k_l1t<<<dim3(NSEQ / TT1, 1, NBATCH), 256, 0, stream>>>(values, L1w, L1b, A);

  float* cur = A;
  float* nxt = Bb;

  for (int blk = 0; blk < 2; ++blk) {
    const float* ehw = ec_hp_w + (size_t)blk * WTS;
    const float* ehb = ec_hp_b + (size_t)blk * CKCH;
    const float* elw = ec_lp_w + (size_t)blk * WTS;
    const float* elb = ec_lp_b + (size_t)blk * CKCH;
    const float* hwr = hp_wr + (size_t)blk * CKCH * CKCH * 16;
    const float* hwi = hp_wi + (size_t)blk * CKCH * CKCH * 16;
    const float* lwr = lp_wr + (size_t)blk * CKCH * CKCH * 16;
    const float* lwi = lp_wi + (size_t)blk * CKCH * CKCH * 16;
    const float* rlw = rc_lp_w + (size_t)blk * WTS;
    const float* rlb = rc_lp_b + (size_t)blk * CKCH;
    const float* rhw = rc_hp_w + (size_t)blk * WTS;
    const float* rhb = rc_hp_b + (size_t)blk * CKCH;
    const float* WtEH = Wt + (size_t)(0 + blk) * WTS;
    const float* WtEL = Wt + (size_t)(2 + blk) * WTS;
    const float* WtRL = Wt + (size_t)(4 + blk) * WTS;
    const float* WtRH = Wt + (size_t)(6 + blk) * WTS;
    int sbase = blk * 30;

    int L = NSEQ;
    size_t doff = 0;
    for (int lvl = 0; lvl < NLEV; ++lvl) {
      int Lh = L >> 1;
      int l = (Lh / 2 + 1 < 16) ? (Lh / 2 + 1) : 16;
      const double* stIn = (lvl == 0) ? nullptr : stats + 2 * (sbase + 2 * (lvl - 1) + 1);
      long ntIn = 4L * CKCH * (NSEQ >> lvl);
      double* stH = stats + 2 * (sbase + 2 * lvl);
      double* stL = stats + 2 * (sbase + 2 * lvl + 1);

      if (Lh >= 128) {
        int ideal = (Lh == 512) ? 8 : 16;
        int icp = pickICP(Lh, ideal, 2);
        float* PH = PB;
        float* PL = PB + (size_t)icp * NBATCH * CKCH * Lh;
        if (Lh >= 256)
          k_conv2_pd<128><<<dim3(Lh / 128, 16 * icp, NBATCH), dim3(32, 8), 0, stream>>>(
              cur, AB, stIn, ntIn, 1, WtEH, WtEL, PH, PL, L, icp);
        else
          k_conv2_pd<64><<<dim3(Lh / 64, 16 * icp, NBATCH), dim3(16, 8), 0, stream>>>(
              cur, AB, stIn, ntIn, 1, WtEH, WtEL, PH, PL, L, icp);
        long tot4 = (long)NBATCH * CKCH * Lh / 4;
        k_red2d<<<dim3((unsigned)(tot4 / 256)), 256, 0, stream>>>(
            PH, PL, ehb, elb, C1, C1L, CB, Lh, icp, __builtin_ctz(Lh));
      } else if (smallFit) {
        float* PH = PB;
        float* PL = PB + (size_t)ICPS * NBATCH * CKCH * Lh;
        k_conv2_sd<<<dim3(NBATCH * CKCH / 4, ICPS), 256, 0, stream>>>(
            cur, AB, stIn, ntIn, 1, ehw, elw, PH, PL, L);
        long tot = (long)NBATCH * CKCH * Lh;
        k_red2s<<<dim3((unsigned)((tot + 255) / 256)), 256, 0, stream>>>(
            PH, PL, ehb, elb, C1, CB, C1L, CB, Lh, __builtin_ctz(Lh), tot);
      }
      dim3 dgrid(CKCH / 64, (l + 3) / 4, 2 * NBATCH), dblk(64, 4);
      dim3 egrid(CKCH * 16 / 256, EP, 2);
      dim3 igrid(CKCH / 256, (Lh + 3) / 4, 2 * NBATCH);
      k_dft2b<<<dgrid, dblk, 0, stream>>>(C1, C1L, CB, tw, XFr, XFi, Lh, l);
      k_einsum2<<<egrid, 256, 0, stream>>>(XFr, XFi, hwr, hwi, lwr, lwi, OMr, OMi, l);
      k_irfft2b<<<igrid, 256, 0, stream>>>(OMr, OMi, tw, Dd + doff, DB, stH,
                                           nxt, AB, stL, Lh, l);
      float* tmp = cur; cur = nxt; nxt = tmp;
      doff += (size_t)CKCH * Lh;
      L = Lh;
    }

    int Ld = 1;
    for (int lv = 0; lv < NLEV; ++lv) {
      int lvlD = NLEV - 1 - lv;
      size_t od = (size_t)CKCH * (size_t)(1024 - (1024 >> lvlD));
      int L2 = 2 * Ld;
      const double* stA = (lv == 0) ? stats + 2 * (sbase + 19)
                                    : stats + 2 * (sbase + 20 + lv - 1);
      int smA = (lv == 0) ? 1 : 0;
      long ntA = 4L * CKCH * Ld;
      const double* stD = stats + 2 * (sbase + 2 * lvlD);
      long ntD = 4L * CKCH * Ld;
      double* stOut = stats + 2 * (sbase + 20 + lv);

      if (L2 >= 128) {
        int ideal = (L2 == 1024) ? 4 : ((L2 == 512) ? 8 : 16);
        int icp = pickICP(L2, ideal, 1);
        if (L2 >= 512)
          k_conv_rec_p<128><<<dim3(L2 / 128, 16 * icp, NBATCH), dim3(32, 8), 0, stream>>>(
              cur, AB, stA, ntA, smA, Dd + od, DB, stD, ntD, WtRL, WtRH, PB, Ld, icp);
        else
          k_conv_rec_p<64><<<dim3(L2 / 64, 16 * icp, NBATCH), dim3(16, 8), 0, stream>>>(
              cur, AB, stA, ntA, smA, Dd + od, DB, stD, ntD, WtRL, WtRH, PB, Ld, icp);
        long tot4 = (long)NBATCH * CKCH * L2 / 4;
        k_red_rec<<<dim3((unsigned)(tot4 / 256)), 256, 0, stream>>>(
            PB, rlb, rhb, nxt, AB, L2, icp, __builtin_ctz(L2), stOut);
      } else if (smallFit) {
        k_conv_rec_sp<<<dim3(NBATCH * CKCH / 4, ICPS), 256, 0, stream>>>(
            cur, AB, stA, ntA, smA, Dd + od, DB, stD, ntD, rlw, rhw, PB, Ld);
        long tot = (long)NBATCH * CKCH * L2;
        k_red_recs<<<dim3((unsigned)((tot + 255) / 256)), 256, 0, stream>>>(
            PB, rlb, rhb, nxt, AB, L2, __builtin_ctz(L2), tot, stOut);
      }
      float* tmp = cur; cur = nxt; nxt = tmp;
      Ld = L2;
    }

    if (blk == 0) {
      long tot = (long)NBATCH * CKCH * NSEQ;
      k_permute_relu<<<dim3((unsigned)((tot + 255) / 256)), 256, 0, stream>>>(
          cur, stats + 2 * (sbase + 29), tot, nxt);
      float* tmp = cur; cur = nxt; nxt = tmp;
    }
  }

  k_l2<<<dim3(NSEQ / TT2, 1, NBATCH), 256, 0, stream>>>(
      cur, stats + 2 * (30 + 29), (long)NBATCH * CKCH * NSEQ, L2w, L2b, (float*)d_out);
}

// Round 14
// 7723.179 us; speedup vs baseline: 1.1711x; 1.1711x over previous
//
#include <hip/hip_runtime.h>
#include <math.h>

#define CKCH 512
#define NLEV 10
#define NBATCH 4
#define NSEQ 1024
#define TWO_PI_F 6.2831853071795864769f
#define INV_SQRT2 0.70710678118654752440f
#define IC 8
#define EP 4    // einsum i-partitions
#define ICPS 4  // small-conv i-partitions
#define WTS ((size_t)CKCH * CKCH * 7)   // one transposed weight tensor (floats)

// ---------------------------------------------------------------------------
__device__ __forceinline__ void get_affine(const double* st, long ntot, int subMean,
                                           float& r, float& madj) {
  r = 1.f; madj = 0.f;
  if (!st) return;
  double s1 = st[0], s2 = st[1];
  double mean = s1 / (double)ntot;
  double var = (s2 - s1 * mean) / (double)(ntot - 1);
  double rs = 1.0 / sqrt(var);
  r = (float)rs;
  madj = subMean ? (float)(-mean * rs) : 0.f;
}

template<int NTHR>
__device__ __forceinline__ void block_stats(float s, float s2, double* st, int tid) {
  if constexpr (NTHR <= 64) {
    #pragma unroll
    for (int off = NTHR / 2; off > 0; off >>= 1) {
      s += __shfl_down(s, off);
      s2 += __shfl_down(s2, off);
    }
    if (tid == 0) { atomicAdd(st, (double)s); atomicAdd(st + 1, (double)s2); }
  } else {
    #pragma unroll
    for (int off = 32; off > 0; off >>= 1) {
      s += __shfl_down(s, off);
      s2 += __shfl_down(s2, off);
    }
    __shared__ float sh1[NTHR / 64], sh2[NTHR / 64];
    int w = tid >> 6;
    if ((tid & 63) == 0) { sh1[w] = s; sh2[w] = s2; }
    __syncthreads();
    if (tid == 0) {
      float a = 0.f, b = 0.f;
      #pragma unroll
      for (int i = 0; i < NTHR / 64; ++i) { a += sh1[i]; b += sh2[i]; }
      atomicAdd(st, (double)a); atomicAdd(st + 1, (double)b);
    }
  }
}

// XCD-chunked swizzle: contiguous logical ranges per XCD (weight-group major).
__device__ __forceinline__ void xcd_map(int& bx, int& by, int& bz) {
  int nbx = gridDim.x, nby = gridDim.y, nbz = gridDim.z;
  int Nb = nbx * nby * nbz;
  int h = blockIdx.x + nbx * (blockIdx.y + nby * blockIdx.z);
  int lg = ((Nb & 7) == 0) ? ((h & 7) * (Nb >> 3) + (h >> 3)) : h;
  int R = nbx * nbz;
  int grp = lg / R, rr = lg % R;
  bx = rr % nbx;
  bz = rr / nbx;
  by = grp;
}

// ---------------------------------------------------------------------------
// One-time weight transpose: Wt[(o*7+f)*512 + i] = W[(o*512+i)*7 + f]
// ---------------------------------------------------------------------------
__global__ __launch_bounds__(256) void k_wt(const float* __restrict__ src,
                                            float* __restrict__ dst) {
  int idx = blockIdx.x * 256 + threadIdx.x;
  if (idx >= (int)WTS) return;
  int i = idx & 511;
  int r = idx >> 9;
  int f = r % 7, o = r / 7;
  dst[idx] = src[(size_t)o * 3584 + i * 7 + f];
}

// ---------------------------------------------------------------------------
#define TT1 8
__global__ __launch_bounds__(256) void k_l1t(const float* __restrict__ vals,
                                             const float* __restrict__ w,
                                             const float* __restrict__ bias,
                                             float* __restrict__ out) {
  __shared__ float sh[TT1][256];
  int b = blockIdx.z;
  int t0 = blockIdx.x * TT1;
  int tid = threadIdx.x;
  for (int i = tid; i < TT1 * 256; i += 256) {
    int tt = i >> 8, d = i & 255;
    sh[tt][d] = vals[((size_t)(b * NSEQ + t0 + tt)) * 256 + d];
  }
  __syncthreads();
  for (int k = tid; k < CKCH; k += 256) {
    float acc[TT1];
    #pragma unroll
    for (int tt = 0; tt < TT1; ++tt) acc[tt] = 0.f;
    const float* wr = w + (size_t)k * 256;
    for (int d = 0; d < 256; ++d) {
      float wv = wr[d];
      #pragma unroll
      for (int tt = 0; tt < TT1; ++tt) acc[tt] += sh[tt][d] * wv;
    }
    float bv = bias[k];
    #pragma unroll
    for (int tt = 0; tt < TT1; ++tt)
      out[(size_t)b * CKCH * NSEQ + (size_t)k * NSEQ + (t0 + tt)] = acc[tt] + bv;
  }
}

// ---------------------------------------------------------------------------
// DUAL-branch partial-sum tiled stride-2 conv, XCD-swizzled + reg-prefetched.
// ---------------------------------------------------------------------------
template<int TT>
__global__ __launch_bounds__((TT / 4) * 8) void k_conv2_pd(
    const float* __restrict__ X, size_t xbs,
    const double* __restrict__ st, long ntot, int subMean,
    const float* __restrict__ WtH, const float* __restrict__ WtL,
    float* __restrict__ PH, float* __restrict__ PL, int L, int ICP) {
  constexpr int SP = 2 * TT + 8;
  constexpr int NTHR = (TT / 4) * 8;
  constexpr int SPAN = 2 * TT + 6;
  constexpr int NQ = TT / 2 + 3;
  constexpr int XTRIPS = (IC * NQ + NTHR - 1) / NTHR;
  constexpr int WCNT = 32 * 7 * (IC / 4);
  constexpr int WTRIPS = (WCNT + NTHR - 1) / NTHR;
  __shared__ float Xs[IC][SP];
  __shared__ float WsH[IC][32][8], WsL[IC][32][8];
  int tx = threadIdx.x, ty = threadIdx.y;
  int tid = ty * (TT / 4) + tx;
  int bxx, byy, bzz;
  xcd_map(bxx, byy, bzz);
  int b = bzz;
  int t0 = bxx * TT;
  int o0 = (byy & 15) * 32;
  int w = byy >> 4;
  int Lh = L >> 1;
  float r, madj;
  get_affine(st, ntot, subMean, r, madj);
  const float* Xb = X + (size_t)b * xbs;
  int pbase = 2 * t0 - 3;
  int ps = pbase & ~3;
  float accH[4][4], accL[4][4];
  #pragma unroll
  for (int i = 0; i < 4; ++i)
    #pragma unroll
    for (int j = 0; j < 4; ++j) { accH[i][j] = 0.f; accL[i][j] = 0.f; }

  float vx[XTRIPS][4];
  float4 wh_[WTRIPS], wl_[WTRIPS];

  auto loadX = [&](int i0) {
    #pragma unroll
    for (int tr = 0; tr < XTRIPS; ++tr) {
      int idx = tid + tr * NTHR;
      if (idx < IC * NQ) {
        int ii = idx / NQ, qq = idx % NQ;
        int p4 = ps + 4 * qq;
        const float* xr = Xb + (size_t)(i0 + ii) * L;
        if (p4 >= 0 && p4 + 3 < L) {
          float4 t = *(const float4*)&xr[p4];
          vx[tr][0] = t.x; vx[tr][1] = t.y; vx[tr][2] = t.z; vx[tr][3] = t.w;
        } else {
          #pragma unroll
          for (int e = 0; e < 4; ++e) {
            int p = p4 + e;
            vx[tr][e] = (p >= 0 && p < L) ? xr[p] : 0.f;
          }
        }
      }
    }
  };
  auto loadW = [&](int i0) {
    #pragma unroll
    for (int tr = 0; tr < WTRIPS; ++tr) {
      int idx = tid + tr * NTHR;
      if (idx < WCNT) {
        int q = idx % (IC / 4);
        int rest = idx / (IC / 4);
        int f = rest % 7, o = rest / 7;
        size_t gb = ((size_t)(o0 + o) * 7 + f) * 512 + i0 + 4 * q;
        wh_[tr] = *(const float4*)&WtH[gb];
        wl_[tr] = *(const float4*)&WtL[gb];
      }
    }
  };
  auto writeLDS = [&]() {
    #pragma unroll
    for (int tr = 0; tr < XTRIPS; ++tr) {
      int idx = tid + tr * NTHR;
      if (idx < IC * NQ) {
        int ii = idx / NQ, qq = idx % NQ;
        int p4 = ps + 4 * qq;
        #pragma unroll
        for (int e = 0; e < 4; ++e) {
          int p = p4 + e;
          int pp = p - pbase;
          if ((unsigned)pp < (unsigned)SPAN) {
            bool ok = (p >= 0 && p < L);
            Xs[ii][pp] = ok ? fmaf(vx[tr][e], r, madj) : 0.f;
          }
        }
      }
    }
    #pragma unroll
    for (int tr = 0; tr < WTRIPS; ++tr) {
      int idx = tid + tr * NTHR;
      if (idx < WCNT) {
        int q = idx % (IC / 4);
        int rest = idx / (IC / 4);
        int f = rest % 7, o = rest / 7;
        WsH[4 * q + 0][o][f] = wh_[tr].x; WsH[4 * q + 1][o][f] = wh_[tr].y;
        WsH[4 * q + 2][o][f] = wh_[tr].z; WsH[4 * q + 3][o][f] = wh_[tr].w;
        WsL[4 * q + 0][o][f] = wl_[tr].x; WsL[4 * q + 1][o][f] = wl_[tr].y;
        WsL[4 * q + 2][o][f] = wl_[tr].z; WsL[4 * q + 3][o][f] = wl_[tr].w;
      }
    }
  };

  int cpp = (CKCH / IC) / ICP;
  int icBeg = w * cpp, icEnd = icBeg + cpp;
  loadX(icBeg * IC);
  loadW(icBeg * IC);
  for (int ic = icBeg; ic < icEnd; ++ic) {
    if (ic != icBeg) __syncthreads();
    writeLDS();
    __syncthreads();
    if (ic + 1 < icEnd) { loadX((ic + 1) * IC); loadW((ic + 1) * IC); }
    #pragma unroll
    for (int ii = 0; ii < IC; ++ii) {
      float xv[16];
      #pragma unroll
      for (int u = 0; u < 4; ++u)
        *(float4*)&xv[4 * u] = *(const float4*)&Xs[ii][8 * tx + 4 * u];
      #pragma unroll
      for (int oo = 0; oo < 4; ++oo) {
        float wh[8], wl[8];
        *(float4*)&wh[0] = *(const float4*)&WsH[ii][ty + 8 * oo][0];
        *(float4*)&wh[4] = *(const float4*)&WsH[ii][ty + 8 * oo][4];
        *(float4*)&wl[0] = *(const float4*)&WsL[ii][ty + 8 * oo][0];
        *(float4*)&wl[4] = *(const float4*)&WsL[ii][ty + 8 * oo][4];
        #pragma unroll
        for (int tt = 0; tt < 4; ++tt)
          #pragma unroll
          for (int f = 0; f < 7; ++f) {
            float x = xv[2 * tt + f];
            accH[oo][tt] = fmaf(x, wh[f], accH[oo][tt]);
            accL[oo][tt] = fmaf(x, wl[f], accL[oo][tt]);
          }
      }
    }
  }
  size_t pb = ((size_t)w * NBATCH + b) * ((size_t)CKCH * Lh);
  #pragma unroll
  for (int oo = 0; oo < 4; ++oo) {
    int o = o0 + ty + 8 * oo;
    float4 vh = make_float4(accH[oo][0], accH[oo][1], accH[oo][2], accH[oo][3]);
    float4 vl = make_float4(accL[oo][0], accL[oo][1], accL[oo][2], accL[oo][3]);
    *(float4*)&PH[pb + (size_t)o * Lh + t0 + 4 * tx] = vh;
    *(float4*)&PL[pb + (size_t)o * Lh + t0 + 4 * tx] = vl;
  }
}

// dual vectorized reduce + biases
__global__ __launch_bounds__(256) void k_red2d(const float* __restrict__ PH,
                                               const float* __restrict__ PL,
                                               const float* __restrict__ bH,
                                               const float* __restrict__ bL,
                                               float* __restrict__ YH,
                                               float* __restrict__ YL, size_t ybs,
                                               int Lh, int ICP, int lhbits) {
  long i4 = (long)blockIdx.x * 256 + threadIdx.x;
  const long per4 = (long)CKCH * Lh / 4;
  int b = (int)(i4 / per4);
  long rem4 = (i4 % per4) * 4;
  int o = (int)(rem4 >> lhbits);
  const size_t pstr = (size_t)NBATCH * CKCH * Lh;
  size_t base = (size_t)b * CKCH * Lh + rem4;
  float4 sh = make_float4(0.f, 0.f, 0.f, 0.f);
  float4 sl = make_float4(0.f, 0.f, 0.f, 0.f);
  for (int w = 0; w < ICP; ++w) {
    float4 vh = *(const float4*)&PH[(size_t)w * pstr + base];
    float4 vl = *(const float4*)&PL[(size_t)w * pstr + base];
    sh.x += vh.x; sh.y += vh.y; sh.z += vh.z; sh.w += vh.w;
    sl.x += vl.x; sl.y += vl.y; sl.z += vl.z; sl.w += vl.w;
  }
  float bvh = bH[o], bvl = bL[o];
  sh.x += bvh; sh.y += bvh; sh.z += bvh; sh.w += bvh;
  sl.x += bvl; sl.y += bvl; sl.z += bvl; sl.w += bvl;
  *(float4*)&YH[(size_t)b * ybs + rem4] = sh;
  *(float4*)&YL[(size_t)b * ybs + rem4] = sl;
}

// ---------------------------------------------------------------------------
// Small-level DUAL-branch stride-2 conv (original weight layout)
// ---------------------------------------------------------------------------
__global__ __launch_bounds__(256) void k_conv2_sd(
    const float* __restrict__ X, size_t xbs,
    const double* __restrict__ st, long ntot, int subMean,
    const float* __restrict__ WH, const float* __restrict__ WL,
    float* __restrict__ PH, float* __restrict__ PL, int L) {
  int Lh = L >> 1;
  int lane = threadIdx.x & 63;
  int gw = blockIdx.x * 4 + (threadIdx.x >> 6);
  int b = __builtin_amdgcn_readfirstlane(gw >> 9);
  int o = __builtin_amdgcn_readfirstlane(gw & 511);
  int w = blockIdx.y;
  float r, madj;
  get_affine(st, ntot, subMean, r, madj);
  const float* Xb = X + (size_t)b * xbs;
  int p0 = 2 * lane - 3;
  int pc[7]; float msk[7];
  #pragma unroll
  for (int u = 0; u < 7; ++u) {
    int p = p0 + u;
    bool ok = (p >= 0 && p < L);
    pc[u] = ok ? p : 0;
    msk[u] = ok ? 1.f : 0.f;
  }
  const int cpi = CKCH / ICPS;
  const float* wh0 = WH + (size_t)o * (CKCH * 7);
  const float* wl0 = WL + (size_t)o * (CKCH * 7);
  float accH = 0.f, accL = 0.f;
  #pragma unroll 2
  for (int i = w * cpi; i < (w + 1) * cpi; ++i) {
    const float* xr = Xb + (size_t)i * L;
    float xv[7];
    #pragma unroll
    for (int u = 0; u < 7; ++u)
      xv[u] = msk[u] * fmaf(xr[pc[u]], r, madj);
    const float* wh = wh0 + i * 7;
    const float* wl = wl0 + i * 7;
    #pragma unroll
    for (int f = 0; f < 7; ++f) {
      accH = fmaf(xv[f], wh[f], accH);
      accL = fmaf(xv[f], wl[f], accL);
    }
  }
  if (lane < Lh) {
    size_t idx = ((size_t)w * NBATCH + b) * ((size_t)CKCH * Lh) + (size_t)o * Lh + lane;
    PH[idx] = accH;
    PL[idx] = accL;
  }
}

__global__ __launch_bounds__(256) void k_red2s(const float* __restrict__ PH,
                                               const float* __restrict__ PL,
                                               const float* __restrict__ bH,
                                               const float* __restrict__ bL,
                                               float* __restrict__ YH, size_t ybsH,
                                               float* __restrict__ YL, size_t ybsL,
                                               int Lh, int lhbits, long tot) {
  long idx = (long)blockIdx.x * 256 + threadIdx.x;
  if (idx >= tot) return;
  const long per = (long)CKCH * Lh;
  int b = (int)(idx / per);
  long rem = idx % per;
  int o = (int)(rem >> lhbits);
  const size_t pstr = (size_t)NBATCH * CKCH * Lh;
  size_t base = (size_t)b * per + rem;
  float sh = 0.f, sl = 0.f;
  #pragma unroll
  for (int w = 0; w < ICPS; ++w) {
    sh += PH[(size_t)w * pstr + base];
    sl += PL[(size_t)w * pstr + base];
  }
  YH[(size_t)b * ybsH + rem] = sh + bH[o];
  YL[(size_t)b * ybsL + rem] = sl + bL[o];
}

// ---------------------------------------------------------------------------
// Partial-sum tiled reconstruction conv, XCD-swizzled + reg-prefetched.
// ---------------------------------------------------------------------------
template<int TT>
__global__ __launch_bounds__((TT / 4) * 8) void k_conv_rec_p(
    const float* __restrict__ A, size_t abs_,
    const double* __restrict__ stA, long ntA, int smA,
    const float* __restrict__ D, size_t dbs,
    const double* __restrict__ stD, long ntD,
    const float* __restrict__ WtA, const float* __restrict__ WtD,
    float* __restrict__ P, int Ld, int ICP) {
  constexpr int QS = TT / 2 + 8;
  constexpr int NTHR = (TT / 4) * 8;
  constexpr int SPANQ = TT / 2 + 4;
  constexpr int NQ = TT / 8 + 3;
  constexpr int XTRIPS = (IC * NQ + NTHR - 1) / NTHR;
  constexpr int WCNT = 32 * 7 * (IC / 4);
  constexpr int WTRIPS = (WCNT + NTHR - 1) / NTHR;
  __shared__ float As[IC][QS], Ds[IC][QS];
  __shared__ float Was[IC][32][8], Wds[IC][32][8];
  int tx = threadIdx.x, ty = threadIdx.y;
  int tid = ty * (TT / 4) + tx;
  int bxx, byy, bzz;
  xcd_map(bxx, byy, bzz);
  int b = bzz;
  int t0 = bxx * TT;
  int o0 = (byy & 15) * 32;
  int w = byy >> 4;
  int L2 = Ld * 2;
  float rA, mA, rD, mD;
  get_affine(stA, ntA, smA, rA, mA);
  get_affine(stD, ntD, 1, rD, mD);
  const float* Ab = A + (size_t)b * abs_;
  const float* Db = D + (size_t)b * dbs;
  int q0 = t0 / 2 - 2;
  int qs = q0 & ~3;
  float acc[4][4];
  #pragma unroll
  for (int i = 0; i < 4; ++i)
    #pragma unroll
    for (int j = 0; j < 4; ++j) acc[i][j] = 0.f;

  float va_r[XTRIPS][4], vd_r[XTRIPS][4];
  float4 wa_r[WTRIPS], wd_r[WTRIPS];

  auto loadX = [&](int i0) {
    #pragma unroll
    for (int tr = 0; tr < XTRIPS; ++tr) {
      int idx = tid + tr * NTHR;
      if (idx < IC * NQ) {
        int ii = idx / NQ, qq = idx % NQ;
        int q4 = qs + 4 * qq;
        const float* ar = Ab + (size_t)(i0 + ii) * Ld;
        const float* dr = Db + (size_t)(i0 + ii) * Ld;
        if (q4 >= 0 && q4 + 3 < Ld) {
          float4 ta = *(const float4*)&ar[q4];
          float4 td = *(const float4*)&dr[q4];
          va_r[tr][0] = ta.x; va_r[tr][1] = ta.y; va_r[tr][2] = ta.z; va_r[tr][3] = ta.w;
          vd_r[tr][0] = td.x; vd_r[tr][1] = td.y; vd_r[tr][2] = td.z; vd_r[tr][3] = td.w;
        } else {
          #pragma unroll
          for (int e = 0; e < 4; ++e) {
            int q = q4 + e;
            bool ok = (q >= 0 && q < Ld);
            va_r[tr][e] = ok ? ar[ok ? q : 0] : 0.f;
            vd_r[tr][e] = ok ? dr[ok ? q : 0] : 0.f;
          }
        }
      }
    }
  };
  auto loadW = [&](int i0) {
    #pragma unroll
    for (int tr = 0; tr < WTRIPS; ++tr) {
      int idx = tid + tr * NTHR;
      if (idx < WCNT) {
        int q = idx % (IC / 4);
        int rest = idx / (IC / 4);
        int f = rest % 7, o = rest / 7;
        size_t gb = ((size_t)(o0 + o) * 7 + f) * 512 + i0 + 4 * q;
        wa_r[tr] = *(const float4*)&WtA[gb];
        wd_r[tr] = *(const float4*)&WtD[gb];
      }
    }
  };
  auto writeLDS = [&]() {
    #pragma unroll
    for (int tr = 0; tr < XTRIPS; ++tr) {
      int idx = tid + tr * NTHR;
      if (idx < IC * NQ) {
        int ii = idx / NQ, qq = idx % NQ;
        int q4 = qs + 4 * qq;
        #pragma unroll
        for (int e = 0; e < 4; ++e) {
          int q = q4 + e;
          int qq2 = q - q0;
          if ((unsigned)qq2 < (unsigned)SPANQ) {
            bool ok = (q >= 0 && q < Ld);
            As[ii][qq2] = ok ? fmaf(va_r[tr][e], rA, mA) : 0.f;
            Ds[ii][qq2] = ok ? fmaf(vd_r[tr][e], rD, mD) : 0.f;
          }
        }
      }
    }
    #pragma unroll
    for (int tr = 0; tr < WTRIPS; ++tr) {
      int idx = tid + tr * NTHR;
      if (idx < WCNT) {
        int q = idx % (IC / 4);
        int rest = idx / (IC / 4);
        int f = rest % 7, o = rest / 7;
        Was[4 * q + 0][o][f] = wa_r[tr].x; Was[4 * q + 1][o][f] = wa_r[tr].y;
        Was[4 * q + 2][o][f] = wa_r[tr].z; Was[4 * q + 3][o][f] = wa_r[tr].w;
        Wds[4 * q + 0][o][f] = wd_r[tr].x; Wds[4 * q + 1][o][f] = wd_r[tr].y;
        Wds[4 * q + 2][o][f] = wd_r[tr].z; Wds[4 * q + 3][o][f] = wd_r[tr].w;
      }
    }
  };

  int cpp = (CKCH / IC) / ICP;
  int icBeg = w * cpp, icEnd = icBeg + cpp;
  loadX(icBeg * IC);
  loadW(icBeg * IC);
  for (int ic = icBeg; ic < icEnd; ++ic) {
    if (ic != icBeg) __syncthreads();
    writeLDS();
    __syncthreads();
    if (ic + 1 < icEnd) { loadX((ic + 1) * IC); loadW((ic + 1) * IC); }
    #pragma unroll
    for (int ii = 0; ii < IC; ++ii) {
      float av[6], dv[6];
      #pragma unroll
      for (int u = 0; u < 3; ++u) {
        *(float2*)&av[2 * u] = *(const float2*)&As[ii][2 * tx + 2 * u];
        *(float2*)&dv[2 * u] = *(const float2*)&Ds[ii][2 * tx + 2 * u];
      }
      #pragma unroll
      for (int oo = 0; oo < 4; ++oo) {
        float wa[8], wd[8];
        *(float4*)&wa[0] = *(const float4*)&Was[ii][ty + 8 * oo][0];
        *(float4*)&wa[4] = *(const float4*)&Was[ii][ty + 8 * oo][4];
        *(float4*)&wd[0] = *(const float4*)&Wds[ii][ty + 8 * oo][0];
        *(float4*)&wd[4] = *(const float4*)&Wds[ii][ty + 8 * oo][4];
        #pragma unroll
        for (int tt = 0; tt < 4; ++tt) {
          #pragma unroll
          for (int f = 0; f < 7; ++f) {
            const int u = ((tt + f - 3) >> 1) + 2;
            acc[oo][tt] = fmaf(av[u], wa[f], acc[oo][tt]);
            acc[oo][tt] = fmaf(dv[u], wd[f], acc[oo][tt]);
          }
        }
      }
    }
  }
  float* Pb = P + ((size_t)w * NBATCH + b) * ((size_t)CKCH * L2);
  #pragma unroll
  for (int oo = 0; oo < 4; ++oo) {
    int o = o0 + ty + 8 * oo;
    float4 v = make_float4(acc[oo][0], acc[oo][1], acc[oo][2], acc[oo][3]);
    *(float4*)&Pb[(size_t)o * L2 + t0 + 4 * tx] = v;
  }
}

__global__ __launch_bounds__(256) void k_red_rec(const float* __restrict__ P,
                                                 const float* __restrict__ bA,
                                                 const float* __restrict__ bD,
                                                 float* __restrict__ S, size_t sbs,
                                                 int L2, int ICP, int lhbits,
                                                 double* __restrict__ stOut) {
  long i4 = (long)blockIdx.x * 256 + threadIdx.x;
  const long per4 = (long)CKCH * L2 / 4;
  int b = (int)(i4 / per4);
  long rem4 = (i4 % per4) * 4;
  int o = (int)(rem4 >> lhbits);
  const size_t pstr = (size_t)NBATCH * CKCH * L2;
  float4 s = *(const float4*)&P[(size_t)b * CKCH * L2 + rem4];
  for (int w = 1; w < ICP; ++w) {
    float4 v = *(const float4*)&P[(size_t)w * pstr + (size_t)b * CKCH * L2 + rem4];
    s.x += v.x; s.y += v.y; s.z += v.z; s.w += v.w;
  }
  float bv = bA[o] + bD[o];
  s.x += bv; s.y += bv; s.z += bv; s.w += bv;
  *(float4*)&S[(size_t)b * sbs + rem4] = s;
  float ss = s.x + s.y + s.z + s.w;
  float s2 = s.x * s.x + s.y * s.y + s.z * s.z + s.w * s.w;
  block_stats<256>(ss, s2, stOut, threadIdx.x);
}

// ---------------------------------------------------------------------------
// Small-level reconstruction (original weight layout)
// ---------------------------------------------------------------------------
__global__ __launch_bounds__(256) void k_conv_rec_sp(
    const float* __restrict__ A, size_t abs_,
    const double* __restrict__ stA, long ntA, int smA,
    const float* __restrict__ D, size_t dbs,
    const double* __restrict__ stD, long ntD,
    const float* __restrict__ WA, const float* __restrict__ WD,
    float* __restrict__ P, int Ld) {
  int L2 = Ld * 2;
  int lane = threadIdx.x & 63;
  int gw = blockIdx.x * 4 + (threadIdx.x >> 6);
  int b = __builtin_amdgcn_readfirstlane(gw >> 9);
  int o = __builtin_amdgcn_readfirstlane(gw & 511);
  int w = blockIdx.y;
  float rA, mA, rD, mD;
  get_affine(stA, ntA, smA, rA, mA);
  get_affine(stD, ntD, 1, rD, mD);
  const float* Ab = A + (size_t)b * abs_;
  const float* Db = D + (size_t)b * dbs;
  const float* wa0 = WA + (size_t)o * (CKCH * 7);
  const float* wd0 = WD + (size_t)o * (CKCH * 7);
  int t = lane;
  int qt0 = (t - 3) >> 1;
  int par = t & 1;
  int qc[4]; float mskq[4];
  #pragma unroll
  for (int u = 0; u < 4; ++u) {
    int q = qt0 + u;
    bool ok = (q >= 0 && q < Ld);
    qc[u] = ok ? q : 0;
    mskq[u] = ok ? 1.f : 0.f;
  }
  const int cpi = CKCH / ICPS;
  float acc = 0.f;
  #pragma unroll 2
  for (int i = w * cpi; i < (w + 1) * cpi; ++i) {
    const float* ar = Ab + (size_t)i * Ld;
    const float* dr = Db + (size_t)i * Ld;
    float av[4], dv[4];
    #pragma unroll
    for (int u = 0; u < 4; ++u) {
      av[u] = mskq[u] * fmaf(ar[qc[u]], rA, mA);
      dv[u] = mskq[u] * fmaf(dr[qc[u]], rD, mD);
    }
    const float* wa = wa0 + i * 7;
    const float* wd = wd0 + i * 7;
    #pragma unroll
    for (int f = 0; f < 7; ++f) {
      const int ue = (f + 1) >> 1;
      const int uo = f >> 1;
      float ax = par ? av[uo] : av[ue];
      float dx = par ? dv[uo] : dv[ue];
      acc = fmaf(ax, wa[f], acc);
      acc = fmaf(dx, wd[f], acc);
    }
  }
  if (t < L2)
    P[((size_t)w * NBATCH + b) * ((size_t)CKCH * L2) + (size_t)o * L2 + t] = acc;
}

__global__ __launch_bounds__(256) void k_red_recs(const float* __restrict__ P,
                                                  const float* __restrict__ bA,
                                                  const float* __restrict__ bD,
                                                  float* __restrict__ S, size_t sbs,
                                                  int L2, int lhbits, long tot,
                                                  double* __restrict__ stOut) {
  long idx = (long)blockIdx.x * 256 + threadIdx.x;
  float val = 0.f;
  if (idx < tot) {
    const long per = (long)CKCH * L2;
    int b = (int)(idx / per);
    long rem = idx % per;
    int o = (int)(rem >> lhbits);
    const size_t pstr = (size_t)NBATCH * CKCH * L2;
    size_t base = (size_t)b * per + rem;
    float s = 0.f;
    #pragma unroll
    for (int w = 0; w < ICPS; ++w) s += P[(size_t)w * pstr + base];
    val = s + bA[o] + bD[o];
    S[(size_t)b * sbs + rem] = val;
  }
  block_stats<256>(val, val * val, stOut, threadIdx.x);
}

// ---------------------------------------------------------------------------
__global__ void k_mktw(float2* tw) {
  int p = blockIdx.x * 256 + threadIdx.x;
  if (p < 1024) {
    float s, c;
    sincosf(TWO_PI_F * (float)p * (1.0f / 1024.0f), &s, &c);
    tw[p] = make_float2(c, s);
  }
}

// ---------------------------------------------------------------------------
__global__ __launch_bounds__(256) void k_dft2b(const float* __restrict__ H0,
                                               const float* __restrict__ H1, size_t hbs,
                                               const float2* __restrict__ tw,
                                               float* __restrict__ xfr, float* __restrict__ xfi,
                                               int Lh, int l) {
  __shared__ float Hs[64][65];
  __shared__ float2 tws[1024];
  int tx = threadIdx.x, ty = threadIdx.y;
  int tid = ty * 64 + tx;
  for (int idx = tid; idx < 1024; idx += 256) tws[idx] = tw[idx];
  int k = blockIdx.x * 64 + tx;
  int x = blockIdx.y * 4 + ty;
  int z = blockIdx.z;
  int br = z >> 2, b = z & 3;
  const float* Hb = (br ? H1 : H0) + (size_t)b * hbs;
  int step = 1024 / Lh;
  int dp = (x * step) & 1023;
  float ar = 0.f, ai = 0.f;
  for (int m0 = 0; m0 < Lh; m0 += 64) {
    int mc = min(64, Lh - m0);
    __syncthreads();
    for (int idx = tid; idx < mc * 64; idx += 256) {
      int mm = idx >> 6, kk = idx & 63;
      Hs[mm][kk] = Hb[(size_t)(m0 + mm) * CKCH + blockIdx.x * 64 + kk];
    }
    __syncthreads();
    int p = (int)(((long)dp * m0) & 1023);
    for (int mm = 0; mm < mc; ++mm) {
      float2 w = tws[p];
      float v = Hs[mm][tx];
      ar = fmaf(v, w.x, ar);
      ai = fmaf(v, -w.y, ai);
      p = (p + dp) & 1023;
    }
  }
  if (x < l) {
    size_t base = ((size_t)(br * NBATCH + b) * CKCH + k) * 16 + x;
    xfr[base] = ar;
    xfi[base] = ai;
  }
}

// ---------------------------------------------------------------------------
__global__ __launch_bounds__(256) void k_einsum2(const float* __restrict__ xfr,
                                                 const float* __restrict__ xfi,
                                                 const float* __restrict__ hwr,
                                                 const float* __restrict__ hwi,
                                                 const float* __restrict__ lwr,
                                                 const float* __restrict__ lwi,
                                                 float* __restrict__ outr,
                                                 float* __restrict__ outi, int l) {
  int gid = blockIdx.x * 256 + threadIdx.x;
  int o = gid >> 4, x = gid & 15;
  if (x >= l) return;
  int part = blockIdx.y;
  int br = blockIdx.z;
  const float* wr = br ? lwr : hwr;
  const float* wi = br ? lwi : hwi;
  int i0 = part * (CKCH / EP);
  float ar[NBATCH] = {0, 0, 0, 0}, ai[NBATCH] = {0, 0, 0, 0};
  size_t xoff = (size_t)(br * NBATCH) * CKCH * 16;
  for (int i = i0; i < i0 + CKCH / EP; ++i) {
    float wre = wr[((size_t)i * CKCH + o) * 16 + x];
    float wim = wi[((size_t)i * CKCH + o) * 16 + x];
    #pragma unroll
    for (int b = 0; b < NBATCH; ++b) {
      float xre = xfr[xoff + ((size_t)b * CKCH + i) * 16 + x];
      float xim = xfi[xoff + ((size_t)b * CKCH + i) * 16 + x];
      ar[b] += xre * wre - xim * wim;
      ai[b] += xre * wim + xim * wre;
    }
  }
  size_t pb = (size_t)part * (2 * NBATCH * CKCH * 16) + xoff;
  #pragma unroll
  for (int b = 0; b < NBATCH; ++b) {
    outr[pb + ((size_t)b * CKCH + o) * 16 + x] = ar[b];
    outi[pb + ((size_t)b * CKCH + o) * 16 + x] = ai[b];
  }
}

// ---------------------------------------------------------------------------
__global__ __launch_bounds__(256) void k_irfft2b(const float* __restrict__ outr,
                                                 const float* __restrict__ outi,
                                                 const float2* __restrict__ tw,
                                                 float* __restrict__ YH, size_t ybsH,
                                                 double* __restrict__ stH,
                                                 float* __restrict__ YL, size_t ybsL,
                                                 double* __restrict__ stL,
                                                 int Lh, int l) {
  int k = blockIdx.x * 256 + threadIdx.x;
  int z = blockIdx.z;
  int br = z >> 2, b = z & 3;
  int t0 = blockIdx.y * 4;
  int step = 1024 / Lh;
  float invL = 1.0f / (float)Lh;
  float acc[4] = {0.f, 0.f, 0.f, 0.f};
  size_t base = ((size_t)(br * NBATCH + b) * CKCH + k) * 16;
  const size_t pstride = (size_t)2 * NBATCH * CKCH * 16;
  for (int x = 0; x < l; ++x) {
    float re = 0.f, im = 0.f;
    #pragma unroll
    for (int p = 0; p < EP; ++p) {
      re += outr[p * pstride + base + x];
      im += outi[p * pstride + base + x];
    }
    float coef = (x == 0 || 2 * x == Lh) ? 1.f : 2.f;
    float cre = coef * re, cim = coef * im;
    #pragma unroll
    for (int tt = 0; tt < 4; ++tt) {
      int t = t0 + tt;
      int p = (x * t * step) & 1023;
      float2 w = tw[p];
      acc[tt] = fmaf(cre, w.x, fmaf(-cim, w.y, acc[tt]));
    }
  }
  float* Y = br ? YL : YH;
  size_t ybs = br ? ybsL : ybsH;
  double* st = br ? stL : stH;
  float s = 0.f, s2 = 0.f;
  float* Yb = Y + (size_t)b * ybs;
  #pragma unroll
  for (int tt = 0; tt < 4; ++tt) {
    int t = t0 + tt;
    if (t < Lh) {
      float y = acc[tt] * invL;
      Yb[(size_t)t * CKCH + k] = y;
      s += y; s2 += y * y;
    }
  }
  block_stats<256>(s, s2, st, threadIdx.x);
}

// ---------------------------------------------------------------------------
__global__ __launch_bounds__(256) void k_permute_relu(const float* __restrict__ in,
                                                      const double* __restrict__ st, long ntot,
                                                      float* __restrict__ out) {
  long idx = (long)blockIdx.x * 256 + threadIdx.x;
  const long total = (long)NBATCH * CKCH * NSEQ;
  if (idx >= total) return;
  float r, madj;
  get_affine(st, ntot, 0, r, madj);
  int b = (int)(idx / (CKCH * NSEQ));
  int rr = (int)(idx % (CKCH * NSEQ));
  int k = rr / NSEQ, t = rr % NSEQ;
  float v = in[(size_t)b * CKCH * NSEQ + (size_t)t * CKCH + k] * r;
  out[idx] = fmaxf(v, 0.f) * INV_SQRT2;
}

// ---------------------------------------------------------------------------
#define TT2 8
__global__ __launch_bounds__(256) void k_l2(const float* __restrict__ Vf,
                                            const double* __restrict__ st, long ntot,
                                            const float* __restrict__ w,
                                            const float* __restrict__ bias,
                                            float* __restrict__ out) {
  __shared__ float sh[TT2][CKCH];
  int b = blockIdx.z;
  int m0 = blockIdx.x * TT2;
  int tid = threadIdx.x;
  float r, madj;
  get_affine(st, ntot, 0, r, madj);
  for (int i = tid; i < TT2 * CKCH; i += 256) {
    int tt = i >> 9, k = i & 511;
    float v = Vf[(size_t)b * CKCH * NSEQ + (size_t)(m0 + tt) * CKCH + k] * r;
    sh[tt][k] = fmaxf(v, 0.f) * INV_SQRT2;
  }
  __syncthreads();
  int o = tid;
  float acc[TT2];
  #pragma unroll
  for (int tt = 0; tt < TT2; ++tt) acc[tt] = 0.f;
  const float* wo = w + (size_t)o * CKCH;
  for (int k = 0; k < CKCH; ++k) {
    float wv = wo[k];
    #pragma unroll
    for (int tt = 0; tt < TT2; ++tt) acc[tt] += sh[tt][k] * wv;
  }
  float bv = bias[o];
  #pragma unroll
  for (int tt = 0; tt < TT2; ++tt)
    out[((size_t)b * NSEQ + m0 + tt) * 256 + o] = acc[tt] + bv;
}

// ---------------------------------------------------------------------------
extern "C" void kernel_launch(void* const* d_in, const int* in_sizes, int n_in,
                              void* d_out, int out_size, void* d_ws, size_t ws_size,
                              hipStream_t stream) {
  const float* values  = (const float*)d_in[2];
  const float* L1w     = (const float*)d_in[4];
  const float* L1b     = (const float*)d_in[5];
  const float* L2w     = (const float*)d_in[6];
  const float* L2b     = (const float*)d_in[7];
  const float* ec_hp_w = (const float*)d_in[8];
  const float* ec_hp_b = (const float*)d_in[9];
  const float* ec_lp_w = (const float*)d_in[10];
  const float* ec_lp_b = (const float*)d_in[11];
  const float* hp_wr   = (const float*)d_in[12];
  const float* hp_wi   = (const float*)d_in[13];
  const float* lp_wr   = (const float*)d_in[14];
  const float* lp_wi   = (const float*)d_in[15];
  const float* rc_lp_w = (const float*)d_in[16];
  const float* rc_lp_b = (const float*)d_in[17];
  const float* rc_hp_w = (const float*)d_in[18];
  const float* rc_hp_b = (const float*)d_in[19];

  double* stats = (double*)d_ws;
  float2* tw = (float2*)((char*)d_ws + 2048);
  float* base = (float*)((char*)d_ws + 12288);
  const size_t AB = (size_t)CKCH * NSEQ;
  const size_t CB = (size_t)CKCH * CKCH;
  const size_t XB = (size_t)CKCH * 16;
  const size_t DB = (size_t)CKCH * 1023;

  float* A   = base;
  float* Bb  = A   + (size_t)NBATCH * AB;
  float* C1  = Bb  + (size_t)NBATCH * AB;
  float* C1L = C1  + (size_t)NBATCH * CB;
  float* XFr = C1L + (size_t)NBATCH * CB;
  float* XFi = XFr + (size_t)2 * NBATCH * XB;
  float* OMr = XFi + (size_t)2 * NBATCH * XB;
  float* OMi = OMr + (size_t)2 * NBATCH * XB * EP;
  float* Dd  = OMi + (size_t)2 * NBATCH * XB * EP;
  float* Wt  = Dd + (size_t)NBATCH * DB;   // 8 transposed weight tensors
  float* PB  = Wt + 8 * WTS;
  size_t used_bytes = 12288 + ((size_t)(PB - base)) * sizeof(float);
  size_t pavail = (ws_size > used_bytes) ? (ws_size - used_bytes) : 0;

  auto pickICP = [&](int len, int ideal, int nbuf) -> int {
    int icp = ideal;
    while (icp > 1 && (size_t)nbuf * icp * NBATCH * CKCH * len * sizeof(float) > pavail)
      icp >>= 1;
    return icp < 1 ? 1 : icp;
  };
  bool smallFit = ((size_t)2 * ICPS * NBATCH * CKCH * 64 * sizeof(float)) <= pavail;

  (void)hipMemsetAsync(stats, 0, 2048, stream);
  k_mktw<<<dim3(4), 256, 0, stream>>>(tw);
  const float* wsrc[8] = {ec_hp_w, ec_hp_w + WTS, ec_lp_w, ec_lp_w + WTS,
                          rc_lp_w, rc_lp_w + WTS, rc_hp_w, rc_hp_w + WTS};
  unsigned wtblocks = (unsigned)((WTS + 255) / 256);
  for (int i = 0; i < 8; ++i)
    k_wt<<<dim3(wtblocks), 256, 0, stream>>>(wsrc[i], Wt + (size_t)i * WTS);

  k_l1t<<<dim3(NSEQ / TT1, 1, NBATCH), 256, 0, stream>>>(values, L1w, L1b, A);

  float* cur = A;
  float* nxt = Bb;

  for (int blk = 0; blk < 2; ++blk) {
    const float* ehw = ec_hp_w + (size_t)blk * WTS;
    const float* ehb = ec_hp_b + (size_t)blk * CKCH;
    const float* elw = ec_lp_w + (size_t)blk * WTS;
    const float* elb = ec_lp_b + (size_t)blk * CKCH;
    const float* hwr = hp_wr + (size_t)blk * CKCH * CKCH * 16;
    const float* hwi = hp_wi + (size_t)blk * CKCH * CKCH * 16;
    const float* lwr = lp_wr + (size_t)blk * CKCH * CKCH * 16;
    const float* lwi = lp_wi + (size_t)blk * CKCH * CKCH * 16;
    const float* rlw = rc_lp_w + (size_t)blk * WTS;
    const float* rlb = rc_lp_b + (size_t)blk * CKCH;
    const float* rhw = rc_hp_w + (size_t)blk * WTS;
    const float* rhb = rc_hp_b + (size_t)blk * CKCH;
    const float* WtEH = Wt + (size_t)(0 + blk) * WTS;
    const float* WtEL = Wt + (size_t)(2 + blk) * WTS;
    const float* WtRL = Wt + (size_t)(4 + blk) * WTS;
    const float* WtRH = Wt + (size_t)(6 + blk) * WTS;
    int sbase = blk * 30;

    int L = NSEQ;
    size_t doff = 0;
    for (int lvl = 0; lvl < NLEV; ++lvl) {
      int Lh = L >> 1;
      int l = (Lh / 2 + 1 < 16) ? (Lh / 2 + 1) : 16;
      const double* stIn = (lvl == 0) ? nullptr : stats + 2 * (sbase + 2 * (lvl - 1) + 1);
      long ntIn = 4L * CKCH * (NSEQ >> lvl);
      double* stH = stats + 2 * (sbase + 2 * lvl);
      double* stL = stats + 2 * (sbase + 2 * lvl + 1);

      if (Lh >= 128) {
        int ideal = (Lh == 512) ? 8 : 16;
        int icp = pickICP(Lh, ideal, 2);
        float* PH = PB;
        float* PL = PB + (size_t)icp * NBATCH * CKCH * Lh;
        if (Lh >= 256)
          k_conv2_pd<128><<<dim3(Lh / 128, 16 * icp, NBATCH), dim3(32, 8), 0, stream>>>(
              cur, AB, stIn, ntIn, 1, WtEH, WtEL, PH, PL, L, icp);
        else
          k_conv2_pd<64><<<dim3(Lh / 64, 16 * icp, NBATCH), dim3(16, 8), 0, stream>>>(
              cur, AB, stIn, ntIn, 1, WtEH, WtEL, PH, PL, L, icp);
        long tot4 = (long)NBATCH * CKCH * Lh / 4;
        k_red2d<<<dim3((unsigned)(tot4 / 256)), 256, 0, stream>>>(
            PH, PL, ehb, elb, C1, C1L, CB, Lh, icp, __builtin_ctz(Lh));
      } else if (smallFit) {
        float* PH = PB;
        float* PL = PB + (size_t)ICPS * NBATCH * CKCH * Lh;
        k_conv2_sd<<<dim3(NBATCH * CKCH / 4, ICPS), 256, 0, stream>>>(
            cur, AB, stIn, ntIn, 1, ehw, elw, PH, PL, L);
        long tot = (long)NBATCH * CKCH * Lh;
        k_red2s<<<dim3((unsigned)((tot + 255) / 256)), 256, 0, stream>>>(
            PH, PL, ehb, elb, C1, CB, C1L, CB, Lh, __builtin_ctz(Lh), tot);
      }
      dim3 dgrid(CKCH / 64, (l + 3) / 4, 2 * NBATCH), dblk(64, 4);
      dim3 egrid(CKCH * 16 / 256, EP, 2);
      dim3 igrid(CKCH / 256, (Lh + 3) / 4, 2 * NBATCH);
      k_dft2b<<<dgrid, dblk, 0, stream>>>(C1, C1L, CB, tw, XFr, XFi, Lh, l);
      k_einsum2<<<egrid, 256, 0, stream>>>(XFr, XFi, hwr, hwi, lwr, lwi, OMr, OMi, l);
      k_irfft2b<<<igrid, 256, 0, stream>>>(OMr, OMi, tw, Dd + doff, DB, stH,
                                           nxt, AB, stL, Lh, l);
      float* tmp = cur; cur = nxt; nxt = tmp;
      doff += (size_t)CKCH * Lh;
      L = Lh;
    }

    int Ld = 1;
    for (int lv = 0; lv < NLEV; ++lv) {
      int lvlD = NLEV - 1 - lv;
      size_t od = (size_t)CKCH * (size_t)(1024 - (1024 >> lvlD));
      int L2 = 2 * Ld;
      const double* stA = (lv == 0) ? stats + 2 * (sbase + 19)
                                    : stats + 2 * (sbase + 20 + lv - 1);
      int smA = (lv == 0) ? 1 : 0;
      long ntA = 4L * CKCH * Ld;
      const double* stD = stats + 2 * (sbase + 2 * lvlD);
      long ntD = 4L * CKCH * Ld;
      double* stOut = stats + 2 * (sbase + 20 + lv);

      if (L2 >= 128) {
        int ideal = (L2 == 1024) ? 4 : ((L2 == 512) ? 8 : 16);
        int icp = pickICP(L2, ideal, 1);
        if (L2 >= 512)
          k_conv_rec_p<128><<<dim3(L2 / 128, 16 * icp, NBATCH), dim3(32, 8), 0, stream>>>(
              cur, AB, stA, ntA, smA, Dd + od, DB, stD, ntD, WtRL, WtRH, PB, Ld, icp);
        else
          k_conv_rec_p<64><<<dim3(L2 / 64, 16 * icp, NBATCH), dim3(16, 8), 0, stream>>>(
              cur, AB, stA, ntA, smA, Dd + od, DB, stD, ntD, WtRL, WtRH, PB, Ld, icp);
        long tot4 = (long)NBATCH * CKCH * L2 / 4;
        k_red_rec<<<dim3((unsigned)(tot4 / 256)), 256, 0, stream>>>(
            PB, rlb, rhb, nxt, AB, L2, icp, __builtin_ctz(L2), stOut);
      } else if (smallFit) {
        k_conv_rec_sp<<<dim3(NBATCH * CKCH / 4, ICPS), 256, 0, stream>>>(
            cur, AB, stA, ntA, smA, Dd + od, DB, stD, ntD, rlw, rhw, PB, Ld);
        long tot = (long)NBATCH * CKCH * L2;
        k_red_recs<<<dim3((unsigned)((tot + 255) / 256)), 256, 0, stream>>>(
            PB, rlb, rhb, nxt, AB, L2, __builtin_ctz(L2), tot, stOut);
      }
      float* tmp = cur; cur = nxt; nxt = tmp;
      Ld = L2;
    }

    if (blk == 0) {
      long tot = (long)NBATCH * CKCH * NSEQ;
      k_permute_relu<<<dim3((unsigned)((tot + 255) / 256)), 256, 0, stream>>>(
          cur, stats + 2 * (sbase + 29), tot, nxt);
      float* tmp = cur; cur = nxt; nxt = tmp;
    }
  }

  k_l2<<<dim3(NSEQ / TT2, 1, NBATCH), 256, 0, stream>>>(
      cur, stats + 2 * (30 + 29), (long)NBATCH * CKCH * NSEQ, L2w, L2b, (float*)d_out);
}